// Round 10
// baseline (238.825 us; speedup 1.0000x reference)
//
#include <hip/hip_runtime.h>

#define AS1 __attribute__((address_space(1)))
#define AS3 __attribute__((address_space(3)))

typedef _Float16 half_t;
typedef __attribute__((ext_vector_type(8))) _Float16 f16x8;  // 8 f16 = 4 VGPRs
typedef __attribute__((ext_vector_type(4))) float f32x4;

static constexpr int Bsz = 4096;   // batch
static constexpr int INs = 512;    // input features
static constexpr int Hs  = 1024;   // hidden
static constexpr int BM  = 128;    // batch rows per block
static constexpr int BH  = 32;     // h-cols per block (x4 gates = 128 eff cols)
static constexpr int BK  = 64;     // K-tile
static constexpr int NIT = INs / BK + Hs / BK;   // 8 + 16 = 24 K-iters

static constexpr size_t XN  = (size_t)Bsz * INs;
static constexpr size_t HXN = (size_t)Bsz * Hs;
static constexpr size_t WXN = (size_t)4 * Hs * INs;
static constexpr size_t WHN = (size_t)4 * Hs * Hs;
static constexpr size_t OFF_X  = 0;
static constexpr size_t OFF_HX = XN;
static constexpr size_t OFF_WX = XN + HXN;
static constexpr size_t OFF_WH = XN + HXN + WXN;
static constexpr size_t TOT    = XN + HXN + WXN + WHN;   // 12,582,912 f16

__device__ __forceinline__ float sigm(float x) {
  return 1.0f / (1.0f + __expf(-x));
}
__device__ __forceinline__ float tanh_fast(float x) {
  const float e = __expf(2.0f * x);
  return 1.0f - 2.0f / (e + 1.0f);
}

// fp32 -> fp16 (RNE) of the four matmul operands into ws. Loop-free.
__global__ __launch_bounds__(256)
void cvt_kernel(const float* __restrict__ x, const float* __restrict__ hx,
                const float* __restrict__ wx, const float* __restrict__ wh,
                half_t* __restrict__ ws) {
  const size_t cid = (size_t)blockIdx.x * 256 + threadIdx.x;
  const size_t e = cid * 8;
  const float* src; size_t off;
  if (e < OFF_HX)      { src = x;  off = e - OFF_X; }
  else if (e < OFF_WX) { src = hx; off = e - OFF_HX; }
  else if (e < OFF_WH) { src = wx; off = e - OFF_WX; }
  else                 { src = wh; off = e - OFF_WH; }
  const f32x4 a = *(const f32x4*)(src + off);
  const f32x4 b = *(const f32x4*)(src + off + 4);
  f16x8 o;
  o[0]=(half_t)a[0]; o[1]=(half_t)a[1]; o[2]=(half_t)a[2]; o[3]=(half_t)a[3];
  o[4]=(half_t)b[0]; o[5]=(half_t)b[1]; o[6]=(half_t)b[2]; o[7]=(half_t)b[3];
  *(f16x8*)(ws + e) = o;
}

// GEMM: A (activations) double-buffered in LDS via global_load_lds (2x16 KB
// = 32 KB -> 4 blocks/CU retained); W read straight from global into VGPRs
// (L2-hot; per instruction 16 rows x 64 B contiguous). stage(it+1) issues
// before compute(it) so the barrier drain covers loads one compute-phase old.
// Wave tiling 2x2: wave (wr,wc) -> rows wr*64+mt*16; B-frag col c =
// wc*64+nt*16+l15 -> gate = nt, h = h0 + wc*16 + l15 (all 4 gates lane-local).
__global__ __launch_bounds__(256, 4)
void plstm_gemm(const half_t* __restrict__ xin,   // [B,IN]  f16
                const half_t* __restrict__ hxp,   // [B,H]   f16
                const float* __restrict__ cxp,    // [B,H]
                const half_t* __restrict__ wxh,   // [4H,IN] f16
                const float* __restrict__ biasp,  // [4H]
                const half_t* __restrict__ whh,   // [4H,H]  f16
                const float* __restrict__ timep,  // [B]
                const float* __restrict__ taup,   // [H]
                const float* __restrict__ sp,     // [H]
                const float* __restrict__ alphap, // [1]
                const float* __restrict__ rhop,   // [1]
                float* __restrict__ outp)         // [2,B,H] = hy ; cy
{
  // XOR-swizzled 16B-chunk layout: slot (row e, c8) holds global chunk c8^(e&7).
  __shared__ half_t As[2][BM * BK];   // 2 x 16 KB

  const int tid  = threadIdx.x;
  const int w    = tid >> 6;
  const int lane = tid & 63;
  const int l15  = lane & 15;
  const int grp  = lane >> 4;
  const int wr   = w >> 1;
  const int wc   = w & 1;

  const int m0 = blockIdx.x * BM;
  const int h0 = blockIdx.y * BH;
  const int hcol = h0 + wc * 16 + l15;   // this lane's h for B-frags/epilogue

  f32x4 acc[4][4] = {};              // [m-subtile][gate]

  const int ldr = tid >> 3;          // 0..31
  const int ldc = tid & 7;           // 16B chunk col 0..7

  auto stageA = [&](int it, int buf) {
    const bool p1 = it >= INs / BK;
    const half_t* Ap = p1 ? hxp : xin;
    const int Ka = p1 ? Hs : INs;
    const int k0 = (p1 ? (it - INs / BK) : it) * BK;
    #pragma unroll
    for (int i = 0; i < 4; ++i) {
      const int e   = i * 32 + ldr;
      const int gc8 = ldc ^ (e & 7);             // swizzle on global side
      const half_t* ga = Ap + (size_t)(m0 + e) * Ka + (k0 + gc8 * 8);
      __builtin_amdgcn_global_load_lds((AS1 void*)ga,
                                       (AS3 void*)(&As[buf][(e * 8 + ldc) * 8]), 16, 0, 0);
    }
  };

  stageA(0, 0);
  __syncthreads();

  for (int it = 0; it < NIT; ++it) {
    const bool p1 = it >= INs / BK;
    const half_t* Wp = p1 ? whh : wxh;
    const int Ka = p1 ? Hs : INs;
    const int k0 = (p1 ? (it - INs / BK) : it) * BK;

    if (it + 1 < NIT) stageA(it + 1, (it + 1) & 1);

    // Issue all 8 W-fragment loads for this iter (global, L2-hot).
    f16x8 bfr[2][4];
    #pragma unroll
    for (int kk = 0; kk < 2; ++kk)
      #pragma unroll
      for (int nt = 0; nt < 4; ++nt)
        bfr[kk][nt] = *(const f16x8*)(Wp + (size_t)(nt * Hs + hcol) * Ka
                                      + k0 + (kk * 4 + grp) * 8);

    const half_t* as = As[it & 1];
    #pragma unroll
    for (int kk = 0; kk < 2; ++kk) {
      const int c8x = kk * 4 + grp;
      f16x8 af[4];
      #pragma unroll
      for (int mt = 0; mt < 4; ++mt) {
        const int e = wr * 64 + mt * 16 + l15;   // e&7 == l15&7
        af[mt] = *(const f16x8*)(as + (e * 8 + (c8x ^ (l15 & 7))) * 8);
      }
      #pragma unroll
      for (int mt = 0; mt < 4; ++mt)
        #pragma unroll
        for (int nt = 0; nt < 4; ++nt)
          acc[mt][nt] = __builtin_amdgcn_mfma_f32_16x16x32_f16(
              af[mt], bfr[kk][nt], acc[mt][nt], 0, 0, 0);
    }
    __syncthreads();   // publishes stage(it+1); As[it&1] free for reuse at it+2
  }

  // ---- fused epilogue: each thread owns ONE h and 16 batch rows ----
  const int h = hcol;
  const float bi  = biasp[h];
  const float bfv = biasp[Hs + h];
  const float bg  = biasp[2 * Hs + h];
  const float bo  = biasp[3 * Hs + h];
  const float sv = sp[h], tauv = taup[h];
  const float alphav = alphap[0], rhov = rhop[0], rh = 0.5f * rhov;

  #pragma unroll
  for (int mt = 0; mt < 4; ++mt) {
    #pragma unroll
    for (int r = 0; r < 4; ++r) {
      // C/D layout (m89-verified): col = lane&15, row = grp*4 + reg
      const int brow = m0 + wr * 64 + mt * 16 + grp * 4 + r;
      const float tv = timep[brow];
      const float phi = fmodf(tv - sv, tauv) / tauv;
      float kv;
      if (phi < rh)        kv = (2.0f * phi) / rhov;
      else if (phi < rhov) kv = 2.0f - (2.0f * phi) / rhov;
      else                 kv = alphav * phi;

      const float iv = acc[mt][0][r] + bi;
      const float fv = acc[mt][1][r] + bfv;
      const float gv = acc[mt][2][r] + bg;
      const float ov = acc[mt][3][r] + bo;
      const float cxv = cxp[(size_t)brow * Hs + h];
      const float ft = sigm(fv + 1.0f - kv);
      const float it2 = sigm(iv) * kv;
      const float gt = tanh_fast(gv) * kv;
      const float ot = sigm(ov) * kv;
      const float cy = ft * cxv + it2 * gt;
      const float hy = ot * tanh_fast(cy);

      outp[(size_t)brow * Hs + h] = hy;
      outp[(size_t)Bsz * Hs + (size_t)brow * Hs + h] = cy;
    }
  }
}

// Fallback (no usable ws): single kernel, fp32 converted during staging.
__global__ __launch_bounds__(256, 3)
void plstm_gemm_f32(const float* __restrict__ xin, const float* __restrict__ timep,
                    const float* __restrict__ hxp, const float* __restrict__ cxp,
                    const float* __restrict__ wxh, const float* __restrict__ biasp,
                    const float* __restrict__ whh, const float* __restrict__ taup,
                    const float* __restrict__ sp, const float* __restrict__ alphap,
                    const float* __restrict__ rhop, float* __restrict__ outp)
{
  __shared__ half_t As[BM * BK];
  __shared__ half_t Bs[BM * BK];

  const int tid  = threadIdx.x;
  const int w    = tid >> 6;
  const int lane = tid & 63;
  const int l15  = lane & 15;
  const int grp  = lane >> 4;
  const int wr   = w >> 1;
  const int wc   = w & 1;

  const int m0 = blockIdx.x * BM;
  const int h0 = blockIdx.y * BH;

  f32x4 acc[4][4] = {};
  const int ldr = tid >> 3;
  const int ldc = tid & 7;

  for (int it = 0; it < NIT; ++it) {
    const bool p1 = it >= INs / BK;
    const float* Ap = p1 ? hxp : xin;
    const float* Wp = p1 ? whh : wxh;
    const int Ka = p1 ? Hs : INs;
    const int k0 = (p1 ? (it - INs / BK) : it) * BK;
    #pragma unroll
    for (int i = 0; i < 4; ++i) {
      const int e    = i * 32 + ldr;
      const int gc8  = ldc ^ (e & 7);
      const int wrow = ((e >> 4) & 3) * Hs + h0 + ((e >> 6) << 4) + (e & 15);
      const float* ga = Ap + (size_t)(m0 + e) * Ka + (k0 + gc8 * 8);
      const f32x4 a0 = *(const f32x4*)ga, a1 = *(const f32x4*)(ga + 4);
      f16x8 pa;
      pa[0]=(half_t)a0[0]; pa[1]=(half_t)a0[1]; pa[2]=(half_t)a0[2]; pa[3]=(half_t)a0[3];
      pa[4]=(half_t)a1[0]; pa[5]=(half_t)a1[1]; pa[6]=(half_t)a1[2]; pa[7]=(half_t)a1[3];
      *(f16x8*)(As + (e * 8 + ldc) * 8) = pa;
      const float* gw = Wp + (size_t)wrow * Ka + (k0 + gc8 * 8);
      const f32x4 b0 = *(const f32x4*)gw, b1 = *(const f32x4*)(gw + 4);
      f16x8 pb;
      pb[0]=(half_t)b0[0]; pb[1]=(half_t)b0[1]; pb[2]=(half_t)b0[2]; pb[3]=(half_t)b0[3];
      pb[4]=(half_t)b1[0]; pb[5]=(half_t)b1[1]; pb[6]=(half_t)b1[2]; pb[7]=(half_t)b1[3];
      *(f16x8*)(Bs + (e * 8 + ldc) * 8) = pb;
    }
    __syncthreads();
    #pragma unroll
    for (int kk = 0; kk < 2; ++kk) {
      const int c8x = kk * 4 + grp;
      f16x8 af[4], bfr[4];
      #pragma unroll
      for (int mt = 0; mt < 4; ++mt) {
        const int e = wr * 64 + mt * 16 + l15;
        af[mt] = *(const f16x8*)(As + (e * 8 + (c8x ^ (l15 & 7))) * 8);
      }
      #pragma unroll
      for (int nt = 0; nt < 4; ++nt) {
        const int e = wc * 64 + nt * 16 + l15;
        bfr[nt] = *(const f16x8*)(Bs + (e * 8 + (c8x ^ (l15 & 7))) * 8);
      }
      #pragma unroll
      for (int mt = 0; mt < 4; ++mt)
        #pragma unroll
        for (int nt = 0; nt < 4; ++nt)
          acc[mt][nt] = __builtin_amdgcn_mfma_f32_16x16x32_f16(
              af[mt], bfr[nt], acc[mt][nt], 0, 0, 0);
    }
    __syncthreads();
  }

  const int h = h0 + wc * 16 + l15;
  const float bi  = biasp[h];
  const float bfv = biasp[Hs + h];
  const float bg  = biasp[2 * Hs + h];
  const float bo  = biasp[3 * Hs + h];
  const float sv = sp[h], tauv = taup[h];
  const float alphav = alphap[0], rhov = rhop[0], rh = 0.5f * rhov;

  #pragma unroll
  for (int mt = 0; mt < 4; ++mt) {
    #pragma unroll
    for (int r = 0; r < 4; ++r) {
      const int brow = m0 + wr * 64 + mt * 16 + grp * 4 + r;
      const float tv = timep[brow];
      const float phi = fmodf(tv - sv, tauv) / tauv;
      float kv;
      if (phi < rh)        kv = (2.0f * phi) / rhov;
      else if (phi < rhov) kv = 2.0f - (2.0f * phi) / rhov;
      else                 kv = alphav * phi;
      const float iv = acc[mt][0][r] + bi;
      const float fv = acc[mt][1][r] + bfv;
      const float gv = acc[mt][2][r] + bg;
      const float ov = acc[mt][3][r] + bo;
      const float cxv = cxp[(size_t)brow * Hs + h];
      const float ft = sigm(fv + 1.0f - kv);
      const float it2 = sigm(iv) * kv;
      const float gt = tanh_fast(gv) * kv;
      const float ot = sigm(ov) * kv;
      const float cy = ft * cxv + it2 * gt;
      const float hy = ot * tanh_fast(cy);
      outp[(size_t)brow * Hs + h] = hy;
      outp[(size_t)Bsz * Hs + (size_t)brow * Hs + h] = cy;
    }
  }
}

extern "C" void kernel_launch(void* const* d_in, const int* in_sizes, int n_in,
                              void* d_out, int out_size, void* d_ws, size_t ws_size,
                              hipStream_t stream) {
  (void)in_sizes; (void)n_in; (void)out_size;
  const float* xin   = (const float*)d_in[0];
  const float* timep = (const float*)d_in[1];
  const float* hxp   = (const float*)d_in[2];
  const float* cxp   = (const float*)d_in[3];
  const float* wxh   = (const float*)d_in[4];
  const float* biasp = (const float*)d_in[5];
  const float* whh   = (const float*)d_in[6];
  const float* taup  = (const float*)d_in[7];
  const float* sp    = (const float*)d_in[8];
  const float* alphap= (const float*)d_in[9];
  const float* rhop  = (const float*)d_in[10];
  float* outp = (float*)d_out;

  dim3 grid(Bsz / BM, Hs / BH);   // 32 x 32 = 1024 blocks = 4 per CU
  if (ws_size >= TOT * sizeof(half_t)) {
    half_t* ws = (half_t*)d_ws;
    cvt_kernel<<<(int)(TOT / 8 / 256), 256, 0, stream>>>(xin, hxp, wxh, whh, ws);
    plstm_gemm<<<grid, 256, 0, stream>>>(
        ws + OFF_X, ws + OFF_HX, cxp, ws + OFF_WX, biasp, ws + OFF_WH,
        timep, taup, sp, alphap, rhop, outp);
  } else {
    plstm_gemm_f32<<<grid, 256, 0, stream>>>(
        xin, timep, hxp, cxp, wxh, biasp, whh,
        taup, sp, alphap, rhop, outp);
  }
}

// Round 11
// 185.190 us; speedup vs baseline: 1.2896x; 1.2896x over previous
//
#include <hip/hip_runtime.h>

#define AS1 __attribute__((address_space(1)))
#define AS3 __attribute__((address_space(3)))

typedef _Float16 half_t;
typedef __attribute__((ext_vector_type(8))) _Float16 f16x8;  // 8 f16 = 4 VGPRs
typedef __attribute__((ext_vector_type(4))) float f32x4;

static constexpr int Bsz = 4096;   // batch
static constexpr int INs = 512;    // input features
static constexpr int Hs  = 1024;   // hidden
static constexpr int BM  = 128;    // batch rows per block
static constexpr int BH  = 32;     // h-cols per block (x4 gates = 128 eff cols)
static constexpr int BK  = 64;     // K-tile
static constexpr int NIT = INs / BK + Hs / BK;   // 8 + 16 = 24 K-iters

static constexpr size_t XN  = (size_t)Bsz * INs;
static constexpr size_t HXN = (size_t)Bsz * Hs;
static constexpr size_t WXN = (size_t)4 * Hs * INs;
static constexpr size_t WHN = (size_t)4 * Hs * Hs;
static constexpr size_t OFF_X  = 0;
static constexpr size_t OFF_HX = XN;
static constexpr size_t OFF_WX = XN + HXN;
static constexpr size_t OFF_WH = XN + HXN + WXN;
static constexpr size_t TOT    = XN + HXN + WXN + WHN;   // 12,582,912 f16

__device__ __forceinline__ float sigm(float x) {
  return 1.0f / (1.0f + __expf(-x));
}
__device__ __forceinline__ float tanh_fast(float x) {
  const float e = __expf(2.0f * x);
  return 1.0f - 2.0f / (e + 1.0f);
}

// fp32 -> fp16 (RNE) of the four matmul operands into ws. Loop-free;
// grid covers TOT/8 chunks exactly.
__global__ __launch_bounds__(256)
void cvt_kernel(const float* __restrict__ x, const float* __restrict__ hx,
                const float* __restrict__ wx, const float* __restrict__ wh,
                half_t* __restrict__ ws) {
  const size_t cid = (size_t)blockIdx.x * 256 + threadIdx.x;
  const size_t e = cid * 8;
  const float* src; size_t off;
  if (e < OFF_HX)      { src = x;  off = e - OFF_X; }
  else if (e < OFF_WX) { src = hx; off = e - OFF_HX; }
  else if (e < OFF_WH) { src = wx; off = e - OFF_WX; }
  else                 { src = wh; off = e - OFF_WH; }
  const f32x4 a = *(const f32x4*)(src + off);
  const f32x4 b = *(const f32x4*)(src + off + 4);
  f16x8 o;
  o[0]=(half_t)a[0]; o[1]=(half_t)a[1]; o[2]=(half_t)a[2]; o[3]=(half_t)a[3];
  o[4]=(half_t)b[0]; o[5]=(half_t)b[1]; o[6]=(half_t)b[2]; o[7]=(half_t)b[3];
  *(f16x8*)(ws + e) = o;
}

// r8-proven GEMM structure: single-buffer As+Bs staged via global_load_lds,
// 4 blocks/CU co-resident (grid = 1024 = 4 x 256 CUs, 32 KB LDS, 64 VGPR):
// cross-block wave overlap (m114) fills barrier stalls. k computed inline
// in the epilogue (r9-validated code) -- no kp round-trip.
// Wave tiling 2x2: wave (wr,wc) -> rows wr*64+mt*16, eff-cols wc*64+nt*16.
// Eff-col c -> gate (c>>4)&3, h = h0 + (c>>6)*16 + (c&15): all four gates of
// one (b,h) sit in the same lane across acc[mt][0..3].
__global__ __launch_bounds__(256, 4)
void plstm_gemm(const half_t* __restrict__ xin,   // [B,IN]  f16
                const half_t* __restrict__ hxp,   // [B,H]   f16
                const float* __restrict__ cxp,    // [B,H]
                const half_t* __restrict__ wxh,   // [4H,IN] f16
                const float* __restrict__ biasp,  // [4H]
                const half_t* __restrict__ whh,   // [4H,H]  f16
                const float* __restrict__ timep,  // [B]
                const float* __restrict__ taup,   // [H]
                const float* __restrict__ sp,     // [H]
                const float* __restrict__ alphap, // [1]
                const float* __restrict__ rhop,   // [1]
                float* __restrict__ outp)         // [2,B,H] = hy ; cy
{
  // XOR-swizzled 16B-chunk layout: slot (row e, c8) holds global chunk c8^(e&7).
  __shared__ half_t As[BM * BK];    // 16 KB
  __shared__ half_t Bs[BM * BK];    // 16 KB

  const int tid  = threadIdx.x;
  const int w    = tid >> 6;
  const int lane = tid & 63;
  const int l15  = lane & 15;
  const int grp  = lane >> 4;
  const int wr   = w >> 1;
  const int wc   = w & 1;

  const int m0 = blockIdx.x * BM;
  const int h0 = blockIdx.y * BH;

  f32x4 acc[4][4] = {};              // [m-subtile][gate]

  const int ldr = tid >> 3;          // 0..31
  const int ldc = tid & 7;           // 16B chunk col 0..7

  for (int it = 0; it < NIT; ++it) {
    const bool p1 = it >= INs / BK;
    const half_t* Ap = p1 ? hxp : xin;
    const half_t* Wp = p1 ? whh : wxh;
    const int Ka = p1 ? Hs : INs;
    const int k0 = (p1 ? (it - INs / BK) : it) * BK;
    #pragma unroll
    for (int i = 0; i < 4; ++i) {
      const int e    = i * 32 + ldr;
      const int gc8  = ldc ^ (e & 7);            // swizzle on global side
      const int wrow = ((e >> 4) & 3) * Hs + h0 + ((e >> 6) << 4) + (e & 15);
      const half_t* ga = Ap + (size_t)(m0 + e) * Ka + (k0 + gc8 * 8);
      __builtin_amdgcn_global_load_lds((AS1 void*)ga,
                                       (AS3 void*)(As + (e * 8 + ldc) * 8), 16, 0, 0);
      const half_t* gw = Wp + (size_t)wrow * Ka + (k0 + gc8 * 8);
      __builtin_amdgcn_global_load_lds((AS1 void*)gw,
                                       (AS3 void*)(Bs + (e * 8 + ldc) * 8), 16, 0, 0);
    }
    __syncthreads();

    #pragma unroll
    for (int kk = 0; kk < 2; ++kk) {
      const int c8x = kk * 4 + grp;
      f16x8 af[4], bfr[4];
      #pragma unroll
      for (int mt = 0; mt < 4; ++mt) {
        const int e = wr * 64 + mt * 16 + l15;   // e&7 == l15&7
        af[mt] = *(const f16x8*)(As + (e * 8 + (c8x ^ (l15 & 7))) * 8);
      }
      #pragma unroll
      for (int nt = 0; nt < 4; ++nt) {
        const int e = wc * 64 + nt * 16 + l15;
        bfr[nt] = *(const f16x8*)(Bs + (e * 8 + (c8x ^ (l15 & 7))) * 8);
      }
      #pragma unroll
      for (int mt = 0; mt < 4; ++mt)
        #pragma unroll
        for (int nt = 0; nt < 4; ++nt)
          acc[mt][nt] = __builtin_amdgcn_mfma_f32_16x16x32_f16(
              af[mt], bfr[nt], acc[mt][nt], 0, 0, 0);
    }
    __syncthreads();
  }

  // ---- fused epilogue: each thread owns ONE h and 16 batch rows ----
  const int h = h0 + wc * 16 + l15;
  const float bi  = biasp[h];
  const float bfv = biasp[Hs + h];
  const float bg  = biasp[2 * Hs + h];
  const float bo  = biasp[3 * Hs + h];
  const float sv = sp[h], tauv = taup[h];
  const float alphav = alphap[0], rhov = rhop[0], rh = 0.5f * rhov;

  #pragma unroll
  for (int mt = 0; mt < 4; ++mt) {
    #pragma unroll
    for (int r = 0; r < 4; ++r) {
      // C/D layout (m89-verified): col = lane&15, row = grp*4 + reg
      const int brow = m0 + wr * 64 + mt * 16 + grp * 4 + r;
      const float tv = timep[brow];
      const float phi = fmodf(tv - sv, tauv) / tauv;
      float kv;
      if (phi < rh)        kv = (2.0f * phi) / rhov;
      else if (phi < rhov) kv = 2.0f - (2.0f * phi) / rhov;
      else                 kv = alphav * phi;

      const float iv = acc[mt][0][r] + bi;
      const float fv = acc[mt][1][r] + bfv;
      const float gv = acc[mt][2][r] + bg;
      const float ov = acc[mt][3][r] + bo;
      const float cxv = cxp[(size_t)brow * Hs + h];
      const float ft = sigm(fv + 1.0f - kv);
      const float it2 = sigm(iv) * kv;
      const float gt = tanh_fast(gv) * kv;
      const float ot = sigm(ov) * kv;
      const float cy = ft * cxv + it2 * gt;
      const float hy = ot * tanh_fast(cy);

      outp[(size_t)brow * Hs + h] = hy;
      outp[(size_t)Bsz * Hs + (size_t)brow * Hs + h] = cy;
    }
  }
}

// Fallback (no usable ws): single kernel, fp32 converted during staging.
__global__ __launch_bounds__(256, 3)
void plstm_gemm_f32(const float* __restrict__ xin, const float* __restrict__ timep,
                    const float* __restrict__ hxp, const float* __restrict__ cxp,
                    const float* __restrict__ wxh, const float* __restrict__ biasp,
                    const float* __restrict__ whh, const float* __restrict__ taup,
                    const float* __restrict__ sp, const float* __restrict__ alphap,
                    const float* __restrict__ rhop, float* __restrict__ outp)
{
  __shared__ half_t As[BM * BK];
  __shared__ half_t Bs[BM * BK];

  const int tid  = threadIdx.x;
  const int w    = tid >> 6;
  const int lane = tid & 63;
  const int l15  = lane & 15;
  const int grp  = lane >> 4;
  const int wr   = w >> 1;
  const int wc   = w & 1;

  const int m0 = blockIdx.x * BM;
  const int h0 = blockIdx.y * BH;

  f32x4 acc[4][4] = {};
  const int ldr = tid >> 3;
  const int ldc = tid & 7;

  for (int it = 0; it < NIT; ++it) {
    const bool p1 = it >= INs / BK;
    const float* Ap = p1 ? hxp : xin;
    const float* Wp = p1 ? whh : wxh;
    const int Ka = p1 ? Hs : INs;
    const int k0 = (p1 ? (it - INs / BK) : it) * BK;
    #pragma unroll
    for (int i = 0; i < 4; ++i) {
      const int e    = i * 32 + ldr;
      const int gc8  = ldc ^ (e & 7);
      const int wrow = ((e >> 4) & 3) * Hs + h0 + ((e >> 6) << 4) + (e & 15);
      const float* ga = Ap + (size_t)(m0 + e) * Ka + (k0 + gc8 * 8);
      const f32x4 a0 = *(const f32x4*)ga, a1 = *(const f32x4*)(ga + 4);
      f16x8 pa;
      pa[0]=(half_t)a0[0]; pa[1]=(half_t)a0[1]; pa[2]=(half_t)a0[2]; pa[3]=(half_t)a0[3];
      pa[4]=(half_t)a1[0]; pa[5]=(half_t)a1[1]; pa[6]=(half_t)a1[2]; pa[7]=(half_t)a1[3];
      *(f16x8*)(As + (e * 8 + ldc) * 8) = pa;
      const float* gw = Wp + (size_t)wrow * Ka + (k0 + gc8 * 8);
      const f32x4 b0 = *(const f32x4*)gw, b1 = *(const f32x4*)(gw + 4);
      f16x8 pb;
      pb[0]=(half_t)b0[0]; pb[1]=(half_t)b0[1]; pb[2]=(half_t)b0[2]; pb[3]=(half_t)b0[3];
      pb[4]=(half_t)b1[0]; pb[5]=(half_t)b1[1]; pb[6]=(half_t)b1[2]; pb[7]=(half_t)b1[3];
      *(f16x8*)(Bs + (e * 8 + ldc) * 8) = pb;
    }
    __syncthreads();
    #pragma unroll
    for (int kk = 0; kk < 2; ++kk) {
      const int c8x = kk * 4 + grp;
      f16x8 af[4], bfr[4];
      #pragma unroll
      for (int mt = 0; mt < 4; ++mt) {
        const int e = wr * 64 + mt * 16 + l15;
        af[mt] = *(const f16x8*)(As + (e * 8 + (c8x ^ (l15 & 7))) * 8);
      }
      #pragma unroll
      for (int nt = 0; nt < 4; ++nt) {
        const int e = wc * 64 + nt * 16 + l15;
        bfr[nt] = *(const f16x8*)(Bs + (e * 8 + (c8x ^ (l15 & 7))) * 8);
      }
      #pragma unroll
      for (int mt = 0; mt < 4; ++mt)
        #pragma unroll
        for (int nt = 0; nt < 4; ++nt)
          acc[mt][nt] = __builtin_amdgcn_mfma_f32_16x16x32_f16(
              af[mt], bfr[nt], acc[mt][nt], 0, 0, 0);
    }
    __syncthreads();
  }

  const int h = h0 + wc * 16 + l15;
  const float bi  = biasp[h];
  const float bfv = biasp[Hs + h];
  const float bg  = biasp[2 * Hs + h];
  const float bo  = biasp[3 * Hs + h];
  const float sv = sp[h], tauv = taup[h];
  const float alphav = alphap[0], rhov = rhop[0], rh = 0.5f * rhov;

  #pragma unroll
  for (int mt = 0; mt < 4; ++mt) {
    #pragma unroll
    for (int r = 0; r < 4; ++r) {
      const int brow = m0 + wr * 64 + mt * 16 + grp * 4 + r;
      const float tv = timep[brow];
      const float phi = fmodf(tv - sv, tauv) / tauv;
      float kv;
      if (phi < rh)        kv = (2.0f * phi) / rhov;
      else if (phi < rhov) kv = 2.0f - (2.0f * phi) / rhov;
      else                 kv = alphav * phi;
      const float iv = acc[mt][0][r] + bi;
      const float fv = acc[mt][1][r] + bfv;
      const float gv = acc[mt][2][r] + bg;
      const float ov = acc[mt][3][r] + bo;
      const float cxv = cxp[(size_t)brow * Hs + h];
      const float ft = sigm(fv + 1.0f - kv);
      const float it2 = sigm(iv) * kv;
      const float gt = tanh_fast(gv) * kv;
      const float ot = sigm(ov) * kv;
      const float cy = ft * cxv + it2 * gt;
      const float hy = ot * tanh_fast(cy);
      outp[(size_t)brow * Hs + h] = hy;
      outp[(size_t)Bsz * Hs + (size_t)brow * Hs + h] = cy;
    }
  }
}

extern "C" void kernel_launch(void* const* d_in, const int* in_sizes, int n_in,
                              void* d_out, int out_size, void* d_ws, size_t ws_size,
                              hipStream_t stream) {
  (void)in_sizes; (void)n_in; (void)out_size;
  const float* xin   = (const float*)d_in[0];
  const float* timep = (const float*)d_in[1];
  const float* hxp   = (const float*)d_in[2];
  const float* cxp   = (const float*)d_in[3];
  const float* wxh   = (const float*)d_in[4];
  const float* biasp = (const float*)d_in[5];
  const float* whh   = (const float*)d_in[6];
  const float* taup  = (const float*)d_in[7];
  const float* sp    = (const float*)d_in[8];
  const float* alphap= (const float*)d_in[9];
  const float* rhop  = (const float*)d_in[10];
  float* outp = (float*)d_out;

  dim3 grid(Bsz / BM, Hs / BH);   // 32 x 32 = 1024 blocks = 4 per CU
  if (ws_size >= TOT * sizeof(half_t)) {
    half_t* ws = (half_t*)d_ws;
    cvt_kernel<<<(int)(TOT / 8 / 256), 256, 0, stream>>>(xin, hxp, wxh, whh, ws);
    plstm_gemm<<<grid, 256, 0, stream>>>(
        ws + OFF_X, ws + OFF_HX, cxp, ws + OFF_WX, biasp, ws + OFF_WH,
        timep, taup, sp, alphap, rhop, outp);
  } else {
    plstm_gemm_f32<<<grid, 256, 0, stream>>>(
        xin, timep, hxp, cxp, wxh, biasp, whh,
        taup, sp, alphap, rhop, outp);
  }
}